// Round 9
// baseline (353.728 us; speedup 1.0000x reference)
//
#include <hip/hip_runtime.h>

// SepConv: out[b,c,i,j] = sum_{u,v} img[b,c,i+u,j+v] * vert[b,u,i,j] * hori[b,v,i,j]
// B=8, C=3, W=H=512, K=13, Wo=Ho=500.
//
// R9: VOLATILE weight burst. Evidence R4/R5: register preloads of weights
// give max BW potential but the allocator sinks them (VGPR 88/68 measured),
// recreating the serialized cold-load chain. volatile loads cannot be sunk,
// reordered among themselves, or rematerialized: all 26 weight quads
// (13 hori + 13 vert, 104 VGPRs) are issued as ONE in-flight burst per wave
// and stay resident. c-loop inside the thread -> each weight byte fetched
// exactly once (R5's over-fetch fixed). img loads (L1/L3-warm) keep depth-1
// prefetch. No LDS, no barriers, no launch_bounds min (R3 spill lesson).
// 12 waves/CU x 26KB bursts, staggered -> continuous HBM demand.

typedef float vf4 __attribute__((ext_vector_type(4)));

#define KK 13
#define NB 8
#define NC 3
#define IW 512
#define IH 512
#define WO 500
#define HO 500
#define KHW 250000        // WO*HO
#define RS4 62500         // KHW/4: vf4 stride between u-slices
#define QROW 125          // j-quads per row

__global__ __launch_bounds__(256) void sepconv_kernel(
    const float* __restrict__ img,
    const float* __restrict__ hori,
    const float* __restrict__ vert,
    float* __restrict__ out)
{
    const int tj = threadIdx.x;                 // j-quad
    if (tj >= QROW) return;
    const int i = blockIdx.y * 2 + threadIdx.y; // output row
    const int b = blockIdx.z;                   // batch
    const int j0 = tj * 4;

    const size_t wbase = (size_t)b * KK * KHW + (size_t)i * HO + j0;
    const volatile vf4* v4 = (const volatile vf4*)(vert + wbase);
    const volatile vf4* h4 = (const volatile vf4*)(hori + wbase);

    // ---- un-sinkable burst: 26 independent cold loads, one drain ----
    vf4 vw[KK], hw[KK];
    #pragma unroll
    for (int u = 0; u < KK; ++u) vw[u] = v4[(size_t)u * RS4];
    #pragma unroll
    for (int v = 0; v < KK; ++v) hw[v] = h4[(size_t)v * RS4];

    #pragma unroll 1
    for (int c = 0; c < NC; ++c) {
        const float* ibase = img + (((size_t)(b * NC + c) * IW) + i) * IH + j0;

        vf4 acc = (vf4){0.f, 0.f, 0.f, 0.f};

        // pipeline prologue: img row u = 0
        vf4 c0 = *(const vf4*)(ibase + 0);
        vf4 c1 = *(const vf4*)(ibase + 4);
        vf4 c2 = *(const vf4*)(ibase + 8);
        vf4 c3 = *(const vf4*)(ibase + 12);

        #pragma unroll
        for (int u = 0; u < KK; ++u) {
            vf4 n0, n1, n2, n3;
            if (u < KK - 1) {
                const float* rp = ibase + (size_t)(u + 1) * IH;
                n0 = *(const vf4*)(rp + 0);
                n1 = *(const vf4*)(rp + 4);
                n2 = *(const vf4*)(rp + 8);
                n3 = *(const vf4*)(rp + 12);
            }

            float row[16];
            row[0]  = c0.x; row[1]  = c0.y; row[2]  = c0.z; row[3]  = c0.w;
            row[4]  = c1.x; row[5]  = c1.y; row[6]  = c1.z; row[7]  = c1.w;
            row[8]  = c2.x; row[9]  = c2.y; row[10] = c2.z; row[11] = c2.w;
            row[12] = c3.x; row[13] = c3.y; row[14] = c3.z; row[15] = c3.w;

            // horizontal conv with register-resident hori, then fold vert
            vf4 hs = (vf4){0.f, 0.f, 0.f, 0.f};
            #pragma unroll
            for (int v = 0; v < KK; ++v) {
                hs.x += row[0 + v] * hw[v].x;
                hs.y += row[1 + v] * hw[v].y;
                hs.z += row[2 + v] * hw[v].z;
                hs.w += row[3 + v] * hw[v].w;
            }
            acc.x += hs.x * vw[u].x;
            acc.y += hs.y * vw[u].y;
            acc.z += hs.z * vw[u].z;
            acc.w += hs.w * vw[u].w;

            if (u < KK - 1) {
                c0 = n0; c1 = n1; c2 = n2; c3 = n3;
            }
        }

        float* op = out + (((size_t)(b * NC + c) * WO) + i) * HO + j0;
        *(vf4*)op = acc;
    }
}

extern "C" void kernel_launch(void* const* d_in, const int* in_sizes, int n_in,
                              void* d_out, int out_size, void* d_ws, size_t ws_size,
                              hipStream_t stream) {
    const float* img  = (const float*)d_in[0];
    const float* hori = (const float*)d_in[1];
    const float* vert = (const float*)d_in[2];
    float* out = (float*)d_out;

    // block: 128 j-quad lanes x 2 rows; grid: y = row pairs, z = batch
    dim3 block(128, 2, 1);
    dim3 grid(1, WO / 2, NB);
    hipLaunchKernelGGL(sepconv_kernel, grid, block, 0, stream, img, hori, vert, out);
}